// Round 16
// baseline (228.572 us; speedup 1.0000x reference)
//
#include <hip/hip_runtime.h>
#include <stdint.h>

#define S_LEN 4096
#define DMODEL 1024
#define NH 16
#define HDIM 64
#define KSPLIT 2
#define LOG2E 1.44269504088896340736f

typedef __attribute__((ext_vector_type(8))) __bf16 bf16x8;
typedef __attribute__((ext_vector_type(4))) __bf16 bf16x4;
typedef __attribute__((ext_vector_type(2))) __bf16 bf16x2;
typedef __attribute__((ext_vector_type(2))) float f32x2;
typedef __attribute__((ext_vector_type(4))) float f32x4;
typedef __attribute__((ext_vector_type(16))) float f32x16;
typedef __attribute__((ext_vector_type(4))) unsigned int uint32x4;

// async global->LDS, 16B per lane; LDS dest = wave-uniform base + lane*16
__device__ __forceinline__ void gload_lds16(const __bf16* g, __bf16* l) {
  __builtin_amdgcn_global_load_lds(
      (const __attribute__((address_space(1))) void*)g,
      (__attribute__((address_space(3))) void*)l, 16, 0, 0);
}

// ---------------- f32 -> bf16 pack + maskadd precompute -----------------------
__global__ __launch_bounds__(256) void convert_f32_bf16(const float* __restrict__ src,
                                                        __bf16* __restrict__ dst,
                                                        const float* __restrict__ mask,
                                                        float* __restrict__ maskadd) {
  int idx = blockIdx.x * 256 + threadIdx.x;
  f32x4 v = ((const f32x4*)src)[idx];
  bf16x4 o;
#pragma unroll
  for (int i = 0; i < 4; ++i) o[i] = (__bf16)v[i];
  ((bf16x4*)dst)[idx] = o;
  if (idx < S_LEN) maskadd[idx] = (1.0f - mask[idx]) * (-10000.0f * LOG2E);
}

// ---------------- tiled transpose (64x64 tiles) for the f32 weights -----------
template <typename T>
__global__ __launch_bounds__(256) void transpose_tiles(const T* __restrict__ src,
                                                       __bf16* __restrict__ dst,
                                                       int R, int C) {
  src += (size_t)blockIdx.z * R * C;
  dst += (size_t)blockIdx.z * R * C;
  __shared__ __bf16 tile[64][65];
  const int r0 = blockIdx.y * 64, c0 = blockIdx.x * 64;
  const int t = threadIdx.x;
  const int col = t & 63, rsub = t >> 6;
#pragma unroll
  for (int i = 0; i < 16; ++i) {
    int r = rsub + i * 4;
    tile[r][col] = (__bf16)src[(size_t)(r0 + r) * C + (c0 + col)];
  }
  __syncthreads();
#pragma unroll
  for (int i = 0; i < 16; ++i) {
    int r = rsub + i * 4;
    dst[(size_t)(c0 + r) * R + (r0 + col)] = tile[col][r];
  }
}

// ---------------- GEMM: C = A (M x K) * BT^T, BT is (N x K) row-major ---------
// EPI 0: plain f32 store.  EPI 1: QKV epilogue, fused RoPE (Q,K) + V-transpose.
template <int EPI>
__global__ __launch_bounds__(256) void gemm_bt(const __bf16* __restrict__ A,
                                               const __bf16* __restrict__ BT,
                                               __bf16* __restrict__ Cq,
                                               __bf16* __restrict__ Ck,
                                               __bf16* __restrict__ Cvt,
                                               const float* __restrict__ freqs,
                                               float* __restrict__ Cout,
                                               int Kdim, int Ndim) {
  __shared__ __align__(16) __bf16 At[128][32];
  __shared__ __align__(16) __bf16 Bt[128][32];
  const int t = threadIdx.x;
  const int wave = t >> 6, lane = t & 63;
  const int wr = wave >> 1, wc = wave & 1;
  const int lrow = lane & 15, lk = lane >> 4;
  const int bm = blockIdx.x, bn = blockIdx.y;

  f32x4 acc[4][4];
#pragma unroll
  for (int i = 0; i < 4; ++i)
#pragma unroll
    for (int j = 0; j < 4; ++j) acc[i][j] = f32x4{0.f, 0.f, 0.f, 0.f};

  const int arow0 = bm * 128, brow0 = bn * 128;
  const int srow = wave * 16 + (lane >> 2);
  const int scol = (lane & 3) * 8;
  const __bf16* gA0 = &A[(size_t)(arow0 + srow) * Kdim + scol];
  const __bf16* gA1 = &A[(size_t)(arow0 + 64 + srow) * Kdim + scol];
  const __bf16* gB0 = &BT[(size_t)(brow0 + srow) * Kdim + scol];
  const __bf16* gB1 = &BT[(size_t)(brow0 + 64 + srow) * Kdim + scol];
  __bf16* lA0 = &At[wave * 16][0];
  __bf16* lA1 = &At[64 + wave * 16][0];
  __bf16* lB0 = &Bt[wave * 16][0];
  __bf16* lB1 = &Bt[64 + wave * 16][0];

  for (int k0 = 0; k0 < Kdim; k0 += 32) {
    __syncthreads();
    gload_lds16(gA0 + k0, lA0);
    gload_lds16(gA1 + k0, lA1);
    gload_lds16(gB0 + k0, lB0);
    gload_lds16(gB1 + k0, lB1);
    __syncthreads();
    bf16x8 af[4], bfr[4];
#pragma unroll
    for (int mi = 0; mi < 4; ++mi)
      af[mi] = *(const bf16x8*)&At[wr * 64 + mi * 16 + lrow][lk * 8];
#pragma unroll
    for (int ni = 0; ni < 4; ++ni)
      bfr[ni] = *(const bf16x8*)&Bt[wc * 64 + ni * 16 + lrow][lk * 8];
#pragma unroll
    for (int mi = 0; mi < 4; ++mi)
#pragma unroll
      for (int ni = 0; ni < 4; ++ni)
        acc[mi][ni] =
            __builtin_amdgcn_mfma_f32_16x16x32_bf16(af[mi], bfr[ni], acc[mi][ni], 0, 0, 0);
  }

  const int rb = bm * 128 + wr * 64 + lk * 4;
  const int cb = bn * 128 + wc * 64 + lrow;
#pragma unroll
  for (int mi = 0; mi < 4; ++mi)
#pragma unroll
    for (int ni = 0; ni < 4; ++ni) {
      int c = cb + ni * 16;
      if (EPI == 0) {
#pragma unroll
        for (int r = 0; r < 4; ++r)
          Cout[(size_t)(rb + mi * 16 + r) * Ndim + c] = acc[mi][ni][r];
      } else {
        const int type = c >> 10;               // uniform per block (bn>>3)
        const int d = c & 1023;
        const int hh = d >> 6, hd = d & 63;
        if (type == 2) {
          bf16x4 pk;
#pragma unroll
          for (int r = 0; r < 4; ++r) pk[r] = (__bf16)acc[mi][ni][r];
          *(bf16x4*)&Cvt[((size_t)hh * HDIM + hd) * S_LEN + rb + mi * 16] = pk;
        } else {
          __bf16* dp = (type == 0) ? Cq : Ck;
          const int i = hd >> 1;
          const float sgn = (hd & 1) ? 1.0f : -1.0f;
#pragma unroll
          for (int r = 0; r < 4; ++r) {
            int row = rb + mi * 16 + r;
            float v = acc[mi][ni][r];
            float w = __shfl_xor(v, 1);
            f32x2 cs = *(const f32x2*)&freqs[((size_t)row * 32 + i) * 2];
            float out = fmaf(v, cs[0], sgn * w * cs[1]);
            dp[((size_t)hh * S_LEN + row) * HDIM + hd] = (__bf16)out;
          }
        }
      }
    }
}

// ---------------- flash attention, split-K=2, 64 q-rows/wave, KVBLK=128, ------
// global_load_lds staging (pre-swizzled SOURCE + linear LDS dest + swizzled
// read — R14-verified pattern), no-max softmax, swapped-QK^T 32x32x16.
// grid = 512 blocks (16 qb x 16 h x 2 split), 256 thr, (256,2), 64KB LDS.
template <int KS>
__global__ __launch_bounds__(256, 2) void attn_split(const __bf16* __restrict__ Q,
                                                     const __bf16* __restrict__ Kmat,
                                                     const __bf16* __restrict__ Vt,
                                                     const float* __restrict__ maskadd,
                                                     float* __restrict__ Opart,
                                                     float* __restrict__ Lpart) {
  constexpr int KC = S_LEN / KS;        // 2048
  constexpr int NIT = KC / 128;         // 16
  __shared__ __align__(16) __bf16 Kl[2][128][64];   // [buf][key][d], 128B rows, seg^=(key&7)
  __shared__ __align__(16) __bf16 Vl[2][64][128];   // [buf][d][key], 256B rows, seg^=(d&15)

  const int t = threadIdx.x;                    // 0..255
  const int id = blockIdx.x;                    // 0..511
  const int swz = (id & 7) * (16 * NH * KS / 8) + (id >> 3);  // bijective XCD swizzle
  const int h = swz / (16 * KS);
  const int rem = swz % (16 * KS);
  const int qb = rem / KS;
  const int split = rem % KS;
  const int k0 = split * KC;
  const int wave = t >> 6, lane = t & 63;
  const int lq = lane & 31, hi = lane >> 5;
  const int sw = lq & 7;                        // K read swizzle
  const int swv = lq & 15;                      // V read swizzle

  const __bf16* Kh = Kmat + (size_t)h * S_LEN * HDIM;
  const __bf16* Vh = Vt + (size_t)h * HDIM * S_LEN;

  // K DMA: wave fills key-rows [wave*32, wave*32+32), 4 gloads of 8 rows.
  // lane -> row +(lane>>3), seg (lane&7)^(lane>>3)  [inverse of read swizzle]
  const int krl = lane >> 3;
  const __bf16* Kg = Kh + (size_t)(wave * 32 + krl) * HDIM + (((lane & 7) ^ krl) * 8);
  // V DMA: wave fills d-rows [wave*16, wave*16+16), 4 gloads of 4 rows.
  // lane -> row +(lane>>4); source key-seg = (lane&15) ^ (d&15)
  const int vrl = lane >> 4;

  auto stage = [&](int buf, int kb) {
#pragma unroll
    for (int j = 0; j < 4; ++j)
      gload_lds16(Kg + (size_t)(kb + j * 8) * HDIM, &Kl[buf][wave * 32 + j * 8][0]);
#pragma unroll
    for (int i = 0; i < 4; ++i) {
      const int d15 = i * 4 + vrl;              // d & 15 (wave*16 = 0 mod 16)
      const __bf16* src =
          Vh + (size_t)(wave * 16 + d15) * S_LEN + kb + (((lane & 15) ^ d15) * 8);
      gload_lds16(src, &Vl[buf][wave * 16 + i * 4][0]);
    }
  };

  // ---- prologue: stage tile 0
  stage(0, k0);

  // Q fragments for both q-groups (B-operand), UNSCALED
  const __bf16* Qh = Q + ((size_t)h * S_LEN + qb * 256 + wave * 64 + lq) * HDIM;
  bf16x8 qfA[4], qfB[4];
#pragma unroll
  for (int ds = 0; ds < 4; ++ds) {
    qfA[ds] = *(const bf16x8*)(Qh + ds * 16 + hi * 8);
    qfB[ds] = *(const bf16x8*)(Qh + (size_t)32 * HDIM + ds * 16 + hi * 8);
  }

  __syncthreads();  // drains prologue DMA (compiler emits vmcnt(0) before barrier)

  const float SCL = 0.125f * LOG2E;
  float lA = 0.f, lB = 0.f;
  f32x16 oA0, oA1, oB0, oB1;
#pragma unroll
  for (int r = 0; r < 16; ++r) { oA0[r] = 0.f; oA1[r] = 0.f; oB0[r] = 0.f; oB1[r] = 0.f; }

  for (int it = 0; it < NIT; ++it) {
    const int cur = it & 1;
    const int kb = k0 + it * 128;

    // ---- issue next 128-key tile's DMA (hides under this tile's compute)
    if (it < NIT - 1) stage(cur ^ 1, kb + 128);

#pragma unroll
    for (int ksub = 0; ksub < 2; ++ksub) {
      const int rbase = ksub * 64;
      const int kbl = kb + ksub * 64;

      // ---- QK^T swapped, both q-groups share each K fragment read
      f32x16 pA0, pA1, pB0, pB1;
#pragma unroll
      for (int r = 0; r < 16; ++r) { pA0[r] = 0.f; pA1[r] = 0.f; pB0[r] = 0.f; pB1[r] = 0.f; }
      __builtin_amdgcn_s_setprio(1);
#pragma unroll
      for (int ds = 0; ds < 4; ++ds) {
        int sg = ((ds << 1) | hi) ^ sw;
        bf16x8 kf0 = *(const bf16x8*)&Kl[cur][rbase + lq][sg * 8];
        pA0 = __builtin_amdgcn_mfma_f32_32x32x16_bf16(kf0, qfA[ds], pA0, 0, 0, 0);
        pB0 = __builtin_amdgcn_mfma_f32_32x32x16_bf16(kf0, qfB[ds], pB0, 0, 0, 0);
      }
#pragma unroll
      for (int ds = 0; ds < 4; ++ds) {
        int sg = ((ds << 1) | hi) ^ sw;
        bf16x8 kf1 = *(const bf16x8*)&Kl[cur][rbase + lq + 32][sg * 8];
        pA1 = __builtin_amdgcn_mfma_f32_32x32x16_bf16(kf1, qfA[ds], pA1, 0, 0, 0);
        pB1 = __builtin_amdgcn_mfma_f32_32x32x16_bf16(kf1, qfB[ds], pB1, 0, 0, 0);
      }
      __builtin_amdgcn_s_setprio(0);

      // ---- no-max softmax: p = exp2(S_raw*SCL + maskadd)
#pragma unroll
      for (int tq = 0; tq < 4; ++tq) {
        f32x4 ma0 = *(const f32x4*)&maskadd[kbl + tq * 8 + hi * 4];
        f32x4 ma1 = *(const f32x4*)&maskadd[kbl + 32 + tq * 8 + hi * 4];
#pragma unroll
        for (int c = 0; c < 4; ++c) {
          pA0[tq * 4 + c] = exp2f(fmaf(pA0[tq * 4 + c], SCL, ma0[c]));
          pB0[tq * 4 + c] = exp2f(fmaf(pB0[tq * 4 + c], SCL, ma0[c]));
          pA1[tq * 4 + c] = exp2f(fmaf(pA1[tq * 4 + c], SCL, ma1[c]));
          pB1[tq * 4 + c] = exp2f(fmaf(pB1[tq * 4 + c], SCL, ma1[c]));
        }
      }
      {
        float a0 = (pA0[0] + pA0[1]) + (pA0[2] + pA0[3]);
        float a1 = (pA0[4] + pA0[5]) + (pA0[6] + pA0[7]);
        float a2 = (pA0[8] + pA0[9]) + (pA0[10] + pA0[11]);
        float a3 = (pA0[12] + pA0[13]) + (pA0[14] + pA0[15]);
        float b0 = (pA1[0] + pA1[1]) + (pA1[2] + pA1[3]);
        float b1 = (pA1[4] + pA1[5]) + (pA1[6] + pA1[7]);
        float b2 = (pA1[8] + pA1[9]) + (pA1[10] + pA1[11]);
        float b3 = (pA1[12] + pA1[13]) + (pA1[14] + pA1[15]);
        float ps = ((a0 + a1) + (a2 + a3)) + ((b0 + b1) + (b2 + b3));
        ps += __shfl_xor(ps, 32);
        lA += ps;
      }
      {
        float a0 = (pB0[0] + pB0[1]) + (pB0[2] + pB0[3]);
        float a1 = (pB0[4] + pB0[5]) + (pB0[6] + pB0[7]);
        float a2 = (pB0[8] + pB0[9]) + (pB0[10] + pB0[11]);
        float a3 = (pB0[12] + pB0[13]) + (pB0[14] + pB0[15]);
        float b0 = (pB1[0] + pB1[1]) + (pB1[2] + pB1[3]);
        float b1 = (pB1[4] + pB1[5]) + (pB1[6] + pB1[7]);
        float b2 = (pB1[8] + pB1[9]) + (pB1[10] + pB1[11]);
        float b3 = (pB1[12] + pB1[13]) + (pB1[14] + pB1[15]);
        float ps = ((a0 + a1) + (a2 + a3)) + ((b0 + b1) + (b2 + b3));
        ps += __shfl_xor(ps, 32);
        lB += ps;
      }

      // ---- pack both groups to bf16 pairs
      unsigned int tA0[8], tA1[8], tB0[8], tB1[8];
#pragma unroll
      for (int tp = 0; tp < 8; ++tp) {
        bf16x2 wa0, wa1, wb0, wb1;
        wa0[0] = (__bf16)pA0[2 * tp]; wa0[1] = (__bf16)pA0[2 * tp + 1];
        wa1[0] = (__bf16)pA1[2 * tp]; wa1[1] = (__bf16)pA1[2 * tp + 1];
        wb0[0] = (__bf16)pB0[2 * tp]; wb0[1] = (__bf16)pB0[2 * tp + 1];
        wb1[0] = (__bf16)pB1[2 * tp]; wb1[1] = (__bf16)pB1[2 * tp + 1];
        tA0[tp] = __builtin_bit_cast(unsigned int, wa0);
        tA1[tp] = __builtin_bit_cast(unsigned int, wa1);
        tB0[tp] = __builtin_bit_cast(unsigned int, wb0);
        tB1[tp] = __builtin_bit_cast(unsigned int, wb1);
      }

      // ---- PV: V fragments shared across both q-groups; 4 shfl per ks
#pragma unroll
      for (int ks = 0; ks < 4; ++ks) {
        unsigned int a0, a1, a2, a3, b0, b1, b2, b3;
        if (ks == 0)      { a0 = tA0[0]; a1 = tA0[1]; a2 = tA0[2]; a3 = tA0[3];
                            b0 = tB0[0]; b1 = tB0[1]; b2 = tB0[2]; b3 = tB0[3]; }
        else if (ks == 1) { a0 = tA0[4]; a1 = tA0[5]; a2 = tA0[6]; a3 = tA0[7];
                            b0 = tB0[4]; b1 = tB0[5]; b2 = tB0[6]; b3 = tB0[7]; }
        else if (ks == 2) { a0 = tA1[0]; a1 = tA1[1]; a2 = tA1[2]; a3 = tA1[3];
                            b0 = tB1[0]; b1 = tB1[1]; b2 = tB1[2]; b3 = tB1[3]; }
        else              { a0 = tA1[4]; a1 = tA1[5]; a2 = tA1[6]; a3 = tA1[7];
                            b0 = tB1[4]; b1 = tB1[5]; b2 = tB1[6]; b3 = tB1[7]; }
        unsigned int sa0 = hi ? a0 : a2, sa1 = hi ? a1 : a3;
        unsigned int sb0 = hi ? b0 : b2, sb1 = hi ? b1 : b3;
        unsigned int ra0 = (unsigned int)__shfl_xor((int)sa0, 32);
        unsigned int ra1 = (unsigned int)__shfl_xor((int)sa1, 32);
        unsigned int rb0 = (unsigned int)__shfl_xor((int)sb0, 32);
        unsigned int rb1 = (unsigned int)__shfl_xor((int)sb1, 32);
        uint32x4 fa, fb;
        fa[0] = hi ? ra0 : a0; fa[1] = hi ? ra1 : a1;
        fa[2] = hi ? a2 : ra0; fa[3] = hi ? a3 : ra1;
        fb[0] = hi ? rb0 : b0; fb[1] = hi ? rb1 : b1;
        fb[2] = hi ? b2 : rb0; fb[3] = hi ? b3 : rb1;
        bf16x8 fav = __builtin_bit_cast(bf16x8, fa);
        bf16x8 fbv = __builtin_bit_cast(bf16x8, fb);
        const int vsg = (ksub * 8 + (ks << 1) + hi) ^ swv;
        bf16x8 v0 = *(const bf16x8*)&Vl[cur][lq][vsg * 8];
        bf16x8 v1 = *(const bf16x8*)&Vl[cur][lq + 32][vsg * 8];
        __builtin_amdgcn_s_setprio(1);
        oA0 = __builtin_amdgcn_mfma_f32_32x32x16_bf16(v0, fav, oA0, 0, 0, 0);
        oA1 = __builtin_amdgcn_mfma_f32_32x32x16_bf16(v1, fav, oA1, 0, 0, 0);
        oB0 = __builtin_amdgcn_mfma_f32_32x32x16_bf16(v0, fbv, oB0, 0, 0, 0);
        oB1 = __builtin_amdgcn_mfma_f32_32x32x16_bf16(v1, fbv, oB1, 0, 0, 0);
        __builtin_amdgcn_s_setprio(0);
      }
    }

    // ---- barrier: DMA for next tile must land; all waves done with buf
    if (it < NIT - 1) __syncthreads();
  }

  // ---- epilogue: store UNNORMALIZED O (f32) and l for both q-groups
  const int qrowA = qb * 256 + wave * 64 + lq;
  float* OpA = Opart + (((size_t)split * NH + h) * S_LEN + qrowA) * 64;
  float* OpB = OpA + (size_t)32 * 64;
#pragma unroll
  for (int tq = 0; tq < 4; ++tq) {
    f32x4 a, b, c, d;
#pragma unroll
    for (int cc = 0; cc < 4; ++cc) {
      a[cc] = oA0[tq * 4 + cc]; b[cc] = oA1[tq * 4 + cc];
      c[cc] = oB0[tq * 4 + cc]; d[cc] = oB1[tq * 4 + cc];
    }
    *(f32x4*)(OpA + tq * 8 + hi * 4) = a;
    *(f32x4*)(OpA + 32 + tq * 8 + hi * 4) = b;
    *(f32x4*)(OpB + tq * 8 + hi * 4) = c;
    *(f32x4*)(OpB + 32 + tq * 8 + hi * 4) = d;
  }
  if (hi == 0) {
    Lpart[((size_t)split * NH + h) * S_LEN + qrowA] = lA;
    Lpart[((size_t)split * NH + h) * S_LEN + qrowA + 32] = lB;
  }
}

// ---------------- merge the KS partials -> AO (bf16) --------------------------
template <int KS>
__global__ __launch_bounds__(256) void attn_merge(const float* __restrict__ Opart,
                                                  const float* __restrict__ Lpart,
                                                  __bf16* __restrict__ AO) {
  int idx = blockIdx.x * 256 + threadIdx.x;  // NH*S*16 threads
  int dd = (idx & 15) * 4;
  int hq = idx >> 4;                          // h*S + q
  int q = hq & (S_LEN - 1), h = hq >> 12;
  float l = 0.f;
  f32x4 acc = f32x4{0.f, 0.f, 0.f, 0.f};
#pragma unroll
  for (int s = 0; s < KS; ++s) {
    l += Lpart[(size_t)s * NH * S_LEN + hq];
    f32x4 a = *(const f32x4*)&Opart[((size_t)s * NH * S_LEN + hq) * 64 + dd];
#pragma unroll
    for (int c = 0; c < 4; ++c) acc[c] += a[c];
  }
  float inv = 1.0f / fmaxf(l, 1e-30f);
  bf16x4 o;
#pragma unroll
  for (int c = 0; c < 4; ++c) o[c] = (__bf16)(acc[c] * inv);
  *(bf16x4*)&AO[(size_t)q * DMODEL + h * HDIM + dd] = o;
}

// ------------------------------------------------------------------------------
extern "C" void kernel_launch(void* const* d_in, const int* in_sizes, int n_in,
                              void* d_out, int out_size, void* d_ws, size_t ws_size,
                              hipStream_t stream) {
  const float* X = (const float*)d_in[0];
  const float* freqs = (const float*)d_in[1];
  const float* mask = (const float*)d_in[2];
  const float* wq = (const float*)d_in[3];
  const float* wk = (const float*)d_in[4];
  const float* wv = (const float*)d_in[5];
  const float* wo = (const float*)d_in[6];
  float* out = (float*)d_out;

  __bf16* WTqkv = (__bf16*)d_ws;                       // 3072*1024
  __bf16* WoT = WTqkv + 3072 * 1024;                   // 1024*1024
  __bf16* Xb = WoT + 1024 * 1024;                      // 4096*1024
  __bf16* Qb = Xb + (size_t)S_LEN * DMODEL;
  __bf16* Kb = Qb + (size_t)NH * S_LEN * HDIM;
  __bf16* Vtb = Kb + (size_t)NH * S_LEN * HDIM;        // V^T written directly by GEMM
  __bf16* AO = Vtb + (size_t)NH * S_LEN * HDIM;

  float* Opart = (float*)(AO + (size_t)S_LEN * DMODEL);
  float* Lpart = Opart + (size_t)KSPLIT * NH * S_LEN * 64;
  float* maskadd = Lpart + (size_t)KSPLIT * NH * S_LEN;

  convert_f32_bf16<<<dim3(S_LEN * DMODEL / 1024), 256, 0, stream>>>(X, Xb, mask, maskadd);

  transpose_tiles<float><<<dim3(16, 16, 1), 256, 0, stream>>>(wq, WTqkv, 1024, 1024);
  transpose_tiles<float><<<dim3(16, 16, 1), 256, 0, stream>>>(wk, WTqkv + 1024 * 1024, 1024, 1024);
  transpose_tiles<float><<<dim3(16, 16, 1), 256, 0, stream>>>(wv, WTqkv + 2 * 1024 * 1024, 1024, 1024);
  transpose_tiles<float><<<dim3(16, 16, 1), 256, 0, stream>>>(wo, WoT, 1024, 1024);

  // QKV projection with FUSED RoPE (Q,K) + FUSED V-transpose
  gemm_bt<1><<<dim3(32, 24), 256, 0, stream>>>(Xb, WTqkv, Qb, Kb, Vtb, freqs, nullptr, 1024, 3072);

  attn_split<KSPLIT><<<dim3(16 * NH * KSPLIT), 256, 0, stream>>>(Qb, Kb, Vtb, maskadd, Opart, Lpart);
  attn_merge<KSPLIT><<<dim3(NH * S_LEN * 16 / 256), 256, 0, stream>>>(Opart, Lpart, AO);

  gemm_bt<0><<<dim3(32, 8), 256, 0, stream>>>(AO, WoT, nullptr, nullptr, nullptr, nullptr, out, 1024, 1024);
}

// Round 17
// 199.020 us; speedup vs baseline: 1.1485x; 1.1485x over previous
//
#include <hip/hip_runtime.h>
#include <stdint.h>

#define S_LEN 4096
#define DMODEL 1024
#define NH 16
#define HDIM 64
#define KSPLIT 2
#define KCHUNK (S_LEN / KSPLIT)
#define LOG2E 1.44269504088896340736f

typedef __attribute__((ext_vector_type(8))) __bf16 bf16x8;
typedef __attribute__((ext_vector_type(4))) __bf16 bf16x4;
typedef __attribute__((ext_vector_type(2))) __bf16 bf16x2;
typedef __attribute__((ext_vector_type(2))) float f32x2;
typedef __attribute__((ext_vector_type(4))) float f32x4;
typedef __attribute__((ext_vector_type(16))) float f32x16;
typedef __attribute__((ext_vector_type(4))) unsigned int uint32x4;

// async global->LDS, 16B per lane; LDS dest = wave-uniform base + lane*16
__device__ __forceinline__ void gload_lds16(const __bf16* g, __bf16* l) {
  __builtin_amdgcn_global_load_lds(
      (const __attribute__((address_space(1))) void*)g,
      (__attribute__((address_space(3))) void*)l, 16, 0, 0);
}

// ---------------- f32 -> bf16 pack + maskadd precompute -----------------------
__global__ __launch_bounds__(256) void convert_f32_bf16(const float* __restrict__ src,
                                                        __bf16* __restrict__ dst,
                                                        const float* __restrict__ mask,
                                                        float* __restrict__ maskadd) {
  int idx = blockIdx.x * 256 + threadIdx.x;
  f32x4 v = ((const f32x4*)src)[idx];
  bf16x4 o;
#pragma unroll
  for (int i = 0; i < 4; ++i) o[i] = (__bf16)v[i];
  ((bf16x4*)dst)[idx] = o;
  if (idx < S_LEN) maskadd[idx] = (1.0f - mask[idx]) * (-10000.0f * LOG2E);
}

// ---------------- batched weight transpose: all 4 weights in ONE launch -------
// z in [0,4): src = {wq,wk,wv,wo}[z]; dst = WTqkv + z MB-chunk (WoT contiguous).
__global__ __launch_bounds__(256) void transpose_w4(const float* __restrict__ w0,
                                                    const float* __restrict__ w1,
                                                    const float* __restrict__ w2,
                                                    const float* __restrict__ w3,
                                                    __bf16* __restrict__ dstBase) {
  const int z = blockIdx.z;
  const float* src = (z == 0) ? w0 : (z == 1) ? w1 : (z == 2) ? w2 : w3;
  __bf16* dst = dstBase + (size_t)z * 1024 * 1024;
  __shared__ __bf16 tile[64][65];
  const int r0 = blockIdx.y * 64, c0 = blockIdx.x * 64;
  const int t = threadIdx.x;
  const int col = t & 63, rsub = t >> 6;
#pragma unroll
  for (int i = 0; i < 16; ++i) {
    int r = rsub + i * 4;
    tile[r][col] = (__bf16)src[(size_t)(r0 + r) * 1024 + (c0 + col)];
  }
  __syncthreads();
#pragma unroll
  for (int i = 0; i < 16; ++i) {
    int r = rsub + i * 4;
    dst[(size_t)(c0 + r) * 1024 + (r0 + col)] = tile[col][r];
  }
}

// ---------------- GEMM: C = A (M x K) * BT^T, BT is (N x K) row-major ---------
// EPI 0: plain f32 store.  EPI 1: QKV epilogue, fused RoPE (Q,K) + V-transpose.
template <int EPI>
__global__ __launch_bounds__(256) void gemm_bt(const __bf16* __restrict__ A,
                                               const __bf16* __restrict__ BT,
                                               __bf16* __restrict__ Cq,
                                               __bf16* __restrict__ Ck,
                                               __bf16* __restrict__ Cvt,
                                               const float* __restrict__ freqs,
                                               float* __restrict__ Cout,
                                               int Kdim, int Ndim) {
  __shared__ __align__(16) __bf16 At[128][32];
  __shared__ __align__(16) __bf16 Bt[128][32];
  const int t = threadIdx.x;
  const int wave = t >> 6, lane = t & 63;
  const int wr = wave >> 1, wc = wave & 1;
  const int lrow = lane & 15, lk = lane >> 4;
  const int bm = blockIdx.x, bn = blockIdx.y;

  f32x4 acc[4][4];
#pragma unroll
  for (int i = 0; i < 4; ++i)
#pragma unroll
    for (int j = 0; j < 4; ++j) acc[i][j] = f32x4{0.f, 0.f, 0.f, 0.f};

  const int arow0 = bm * 128, brow0 = bn * 128;
  const int srow = wave * 16 + (lane >> 2);
  const int scol = (lane & 3) * 8;
  const __bf16* gA0 = &A[(size_t)(arow0 + srow) * Kdim + scol];
  const __bf16* gA1 = &A[(size_t)(arow0 + 64 + srow) * Kdim + scol];
  const __bf16* gB0 = &BT[(size_t)(brow0 + srow) * Kdim + scol];
  const __bf16* gB1 = &BT[(size_t)(brow0 + 64 + srow) * Kdim + scol];
  __bf16* lA0 = &At[wave * 16][0];
  __bf16* lA1 = &At[64 + wave * 16][0];
  __bf16* lB0 = &Bt[wave * 16][0];
  __bf16* lB1 = &Bt[64 + wave * 16][0];

  for (int k0 = 0; k0 < Kdim; k0 += 32) {
    __syncthreads();
    gload_lds16(gA0 + k0, lA0);
    gload_lds16(gA1 + k0, lA1);
    gload_lds16(gB0 + k0, lB0);
    gload_lds16(gB1 + k0, lB1);
    __syncthreads();
    bf16x8 af[4], bfr[4];
#pragma unroll
    for (int mi = 0; mi < 4; ++mi)
      af[mi] = *(const bf16x8*)&At[wr * 64 + mi * 16 + lrow][lk * 8];
#pragma unroll
    for (int ni = 0; ni < 4; ++ni)
      bfr[ni] = *(const bf16x8*)&Bt[wc * 64 + ni * 16 + lrow][lk * 8];
#pragma unroll
    for (int mi = 0; mi < 4; ++mi)
#pragma unroll
      for (int ni = 0; ni < 4; ++ni)
        acc[mi][ni] =
            __builtin_amdgcn_mfma_f32_16x16x32_bf16(af[mi], bfr[ni], acc[mi][ni], 0, 0, 0);
  }

  const int rb = bm * 128 + wr * 64 + lk * 4;
  const int cb = bn * 128 + wc * 64 + lrow;
#pragma unroll
  for (int mi = 0; mi < 4; ++mi)
#pragma unroll
    for (int ni = 0; ni < 4; ++ni) {
      int c = cb + ni * 16;
      if (EPI == 0) {
#pragma unroll
        for (int r = 0; r < 4; ++r)
          Cout[(size_t)(rb + mi * 16 + r) * Ndim + c] = acc[mi][ni][r];
      } else {
        const int type = c >> 10;               // uniform per block (bn>>3)
        const int d = c & 1023;
        const int hh = d >> 6, hd = d & 63;
        if (type == 2) {
          bf16x4 pk;
#pragma unroll
          for (int r = 0; r < 4; ++r) pk[r] = (__bf16)acc[mi][ni][r];
          *(bf16x4*)&Cvt[((size_t)hh * HDIM + hd) * S_LEN + rb + mi * 16] = pk;
        } else {
          __bf16* dp = (type == 0) ? Cq : Ck;
          const int i = hd >> 1;
          const float sgn = (hd & 1) ? 1.0f : -1.0f;
#pragma unroll
          for (int r = 0; r < 4; ++r) {
            int row = rb + mi * 16 + r;
            float v = acc[mi][ni][r];
            float w = __shfl_xor(v, 1);
            f32x2 cs = *(const f32x2*)&freqs[((size_t)row * 32 + i) * 2];
            float out = fmaf(v, cs[0], sgn * w * cs[1]);
            dp[((size_t)hh * S_LEN + row) * HDIM + hd] = (__bf16)out;
          }
        }
      }
    }
}

// ---------------- flash attention, split-K=2, 64 q-rows/wave (R11 exact) ------
template <int KS>
__global__ __launch_bounds__(256, 2) void attn_split(const __bf16* __restrict__ Q,
                                                     const __bf16* __restrict__ Kmat,
                                                     const __bf16* __restrict__ Vt,
                                                     const float* __restrict__ maskadd,
                                                     float* __restrict__ Opart,
                                                     float* __restrict__ Lpart) {
  constexpr int KC = S_LEN / KS;
  __shared__ __align__(16) __bf16 Kl[2][64][64];       // [buf][key][d], 128B rows
  __shared__ __align__(16) __bf16 Vl[2][64][64];       // [buf][d][key], 128B rows

  const int t = threadIdx.x;                    // 0..255
  const int id = blockIdx.x;                    // 0..16*NH*KS-1
  const int swz = (id & 7) * (16 * NH * KS / 8) + (id >> 3);  // bijective XCD swizzle
  const int h = swz / (16 * KS);
  const int rem = swz % (16 * KS);
  const int qb = rem / KS;
  const int split = rem % KS;
  const int k0 = split * KC;
  const int wave = t >> 6, lane = t & 63;
  const int lq = lane & 31, hi = lane >> 5;
  const int sw = lq & 7;                        // read-side swizzle bits

  const __bf16* Kh = Kmat + (size_t)h * S_LEN * HDIM;
  const __bf16* Vh = Vt + (size_t)h * HDIM * S_LEN;

  // staging coords: each thread stages 32B of K and 32B of V per tile
  const int sr = t >> 2;                        // row 0..63
  const int sc0 = (t & 3) * 2;                  // even 16B segment
  const int scs0 = (sc0 ^ (sr & 7)) * 8;        // write-side swizzled elem offsets
  const int scs1 = ((sc0 + 1) ^ (sr & 7)) * 8;
  const __bf16* Kgb = Kh + (size_t)sr * HDIM + sc0 * 8;   // + kb*HDIM per tile
  const __bf16* Vgb = Vh + (size_t)sr * S_LEN + sc0 * 8;  // + kb per tile

  // ---- prologue: tile 0 staged
  uint32x4 kreg0, kreg1, vreg0, vreg1;
  kreg0 = *(const uint32x4*)(Kgb + (size_t)k0 * HDIM);
  kreg1 = *(const uint32x4*)(Kgb + (size_t)k0 * HDIM + 8);
  vreg0 = *(const uint32x4*)(Vgb + k0);
  vreg1 = *(const uint32x4*)(Vgb + k0 + 8);
  *(uint32x4*)&Kl[0][sr][scs0] = kreg0;
  *(uint32x4*)&Kl[0][sr][scs1] = kreg1;
  *(uint32x4*)&Vl[0][sr][scs0] = vreg0;
  *(uint32x4*)&Vl[0][sr][scs1] = vreg1;

  // Q fragments for both q-groups (B-operand), UNSCALED
  const __bf16* Qh = Q + ((size_t)h * S_LEN + qb * 256 + wave * 64 + lq) * HDIM;
  bf16x8 qfA[4], qfB[4];
#pragma unroll
  for (int ds = 0; ds < 4; ++ds) {
    qfA[ds] = *(const bf16x8*)(Qh + ds * 16 + hi * 8);
    qfB[ds] = *(const bf16x8*)(Qh + (size_t)32 * HDIM + ds * 16 + hi * 8);
  }

  __syncthreads();

  const float SCL = 0.125f * LOG2E;
  float lA = 0.f, lB = 0.f;
  f32x16 oA0, oA1, oB0, oB1;
#pragma unroll
  for (int r = 0; r < 16; ++r) { oA0[r] = 0.f; oA1[r] = 0.f; oB0[r] = 0.f; oB1[r] = 0.f; }

  for (int it = 0; it < KC / 64; ++it) {
    const int cur = it & 1;
    const int kb = k0 + it * 64;

    // ---- issue next tile's global loads (latency hides under this tile's compute)
    if (it < KC / 64 - 1) {
      kreg0 = *(const uint32x4*)(Kgb + (size_t)(kb + 64) * HDIM);
      kreg1 = *(const uint32x4*)(Kgb + (size_t)(kb + 64) * HDIM + 8);
      vreg0 = *(const uint32x4*)(Vgb + (kb + 64));
      vreg1 = *(const uint32x4*)(Vgb + (kb + 64) + 8);
    }

    // ---- QK^T swapped, both q-groups share each K fragment read
    f32x16 pA0, pA1, pB0, pB1;
#pragma unroll
    for (int r = 0; r < 16; ++r) { pA0[r] = 0.f; pA1[r] = 0.f; pB0[r] = 0.f; pB1[r] = 0.f; }
    __builtin_amdgcn_s_setprio(1);
#pragma unroll
    for (int ds = 0; ds < 4; ++ds) {
      int sg = ((ds << 1) | hi) ^ sw;
      bf16x8 kf0 = *(const bf16x8*)&Kl[cur][lq][sg * 8];
      pA0 = __builtin_amdgcn_mfma_f32_32x32x16_bf16(kf0, qfA[ds], pA0, 0, 0, 0);
      pB0 = __builtin_amdgcn_mfma_f32_32x32x16_bf16(kf0, qfB[ds], pB0, 0, 0, 0);
    }
#pragma unroll
    for (int ds = 0; ds < 4; ++ds) {
      int sg = ((ds << 1) | hi) ^ sw;
      bf16x8 kf1 = *(const bf16x8*)&Kl[cur][lq + 32][sg * 8];
      pA1 = __builtin_amdgcn_mfma_f32_32x32x16_bf16(kf1, qfA[ds], pA1, 0, 0, 0);
      pB1 = __builtin_amdgcn_mfma_f32_32x32x16_bf16(kf1, qfB[ds], pB1, 0, 0, 0);
    }
    __builtin_amdgcn_s_setprio(0);

    // ---- no-max softmax: p = exp2(S_raw*SCL + maskadd); mask loads shared A/B
#pragma unroll
    for (int tq = 0; tq < 4; ++tq) {
      f32x4 ma0 = *(const f32x4*)&maskadd[kb + tq * 8 + hi * 4];
      f32x4 ma1 = *(const f32x4*)&maskadd[kb + 32 + tq * 8 + hi * 4];
#pragma unroll
      for (int c = 0; c < 4; ++c) {
        pA0[tq * 4 + c] = exp2f(fmaf(pA0[tq * 4 + c], SCL, ma0[c]));
        pB0[tq * 4 + c] = exp2f(fmaf(pB0[tq * 4 + c], SCL, ma0[c]));
        pA1[tq * 4 + c] = exp2f(fmaf(pA1[tq * 4 + c], SCL, ma1[c]));
        pB1[tq * 4 + c] = exp2f(fmaf(pB1[tq * 4 + c], SCL, ma1[c]));
      }
    }
    {
      float a0 = (pA0[0] + pA0[1]) + (pA0[2] + pA0[3]);
      float a1 = (pA0[4] + pA0[5]) + (pA0[6] + pA0[7]);
      float a2 = (pA0[8] + pA0[9]) + (pA0[10] + pA0[11]);
      float a3 = (pA0[12] + pA0[13]) + (pA0[14] + pA0[15]);
      float b0 = (pA1[0] + pA1[1]) + (pA1[2] + pA1[3]);
      float b1 = (pA1[4] + pA1[5]) + (pA1[6] + pA1[7]);
      float b2 = (pA1[8] + pA1[9]) + (pA1[10] + pA1[11]);
      float b3 = (pA1[12] + pA1[13]) + (pA1[14] + pA1[15]);
      float ps = ((a0 + a1) + (a2 + a3)) + ((b0 + b1) + (b2 + b3));
      ps += __shfl_xor(ps, 32);
      lA += ps;
    }
    {
      float a0 = (pB0[0] + pB0[1]) + (pB0[2] + pB0[3]);
      float a1 = (pB0[4] + pB0[5]) + (pB0[6] + pB0[7]);
      float a2 = (pB0[8] + pB0[9]) + (pB0[10] + pB0[11]);
      float a3 = (pB0[12] + pB0[13]) + (pB0[14] + pB0[15]);
      float b0 = (pB1[0] + pB1[1]) + (pB1[2] + pB1[3]);
      float b1 = (pB1[4] + pB1[5]) + (pB1[6] + pB1[7]);
      float b2 = (pB1[8] + pB1[9]) + (pB1[10] + pB1[11]);
      float b3 = (pB1[12] + pB1[13]) + (pB1[14] + pB1[15]);
      float ps = ((a0 + a1) + (a2 + a3)) + ((b0 + b1) + (b2 + b3));
      ps += __shfl_xor(ps, 32);
      lB += ps;
    }

    // ---- pack both groups to bf16 pairs
    unsigned int tA0[8], tA1[8], tB0[8], tB1[8];
#pragma unroll
    for (int tp = 0; tp < 8; ++tp) {
      bf16x2 wa0, wa1, wb0, wb1;
      wa0[0] = (__bf16)pA0[2 * tp]; wa0[1] = (__bf16)pA0[2 * tp + 1];
      wa1[0] = (__bf16)pA1[2 * tp]; wa1[1] = (__bf16)pA1[2 * tp + 1];
      wb0[0] = (__bf16)pB0[2 * tp]; wb0[1] = (__bf16)pB0[2 * tp + 1];
      wb1[0] = (__bf16)pB1[2 * tp]; wb1[1] = (__bf16)pB1[2 * tp + 1];
      tA0[tp] = __builtin_bit_cast(unsigned int, wa0);
      tA1[tp] = __builtin_bit_cast(unsigned int, wa1);
      tB0[tp] = __builtin_bit_cast(unsigned int, wb0);
      tB1[tp] = __builtin_bit_cast(unsigned int, wb1);
    }

    // ---- PV: V fragments shared across both q-groups; 4 shfl per ks
#pragma unroll
    for (int ks = 0; ks < 4; ++ks) {
      unsigned int a0, a1, a2, a3, b0, b1, b2, b3;
      if (ks == 0)      { a0 = tA0[0]; a1 = tA0[1]; a2 = tA0[2]; a3 = tA0[3];
                          b0 = tB0[0]; b1 = tB0[1]; b2 = tB0[2]; b3 = tB0[3]; }
      else if (ks == 1) { a0 = tA0[4]; a1 = tA0[5]; a2 = tA0[6]; a3 = tA0[7];
                          b0 = tB0[4]; b1 = tB0[5]; b2 = tB0[6]; b3 = tB0[7]; }
      else if (ks == 2) { a0 = tA1[0]; a1 = tA1[1]; a2 = tA1[2]; a3 = tA1[3];
                          b0 = tB1[0]; b1 = tB1[1]; b2 = tB1[2]; b3 = tB1[3]; }
      else              { a0 = tA1[4]; a1 = tA1[5]; a2 = tA1[6]; a3 = tA1[7];
                          b0 = tB1[4]; b1 = tB1[5]; b2 = tB1[6]; b3 = tB1[7]; }
      unsigned int sa0 = hi ? a0 : a2, sa1 = hi ? a1 : a3;
      unsigned int sb0 = hi ? b0 : b2, sb1 = hi ? b1 : b3;
      unsigned int ra0 = (unsigned int)__shfl_xor((int)sa0, 32);
      unsigned int ra1 = (unsigned int)__shfl_xor((int)sa1, 32);
      unsigned int rb0 = (unsigned int)__shfl_xor((int)sb0, 32);
      unsigned int rb1 = (unsigned int)__shfl_xor((int)sb1, 32);
      uint32x4 fa, fb;
      fa[0] = hi ? ra0 : a0; fa[1] = hi ? ra1 : a1;
      fa[2] = hi ? a2 : ra0; fa[3] = hi ? a3 : ra1;
      fb[0] = hi ? rb0 : b0; fb[1] = hi ? rb1 : b1;
      fb[2] = hi ? b2 : rb0; fb[3] = hi ? b3 : rb1;
      bf16x8 fav = __builtin_bit_cast(bf16x8, fa);
      bf16x8 fbv = __builtin_bit_cast(bf16x8, fb);
      int sg = ((ks << 1) | hi) ^ sw;
      bf16x8 v0 = *(const bf16x8*)&Vl[cur][lq][sg * 8];
      bf16x8 v1 = *(const bf16x8*)&Vl[cur][lq + 32][sg * 8];
      __builtin_amdgcn_s_setprio(1);
      oA0 = __builtin_amdgcn_mfma_f32_32x32x16_bf16(v0, fav, oA0, 0, 0, 0);
      oA1 = __builtin_amdgcn_mfma_f32_32x32x16_bf16(v1, fav, oA1, 0, 0, 0);
      oB0 = __builtin_amdgcn_mfma_f32_32x32x16_bf16(v0, fbv, oB0, 0, 0, 0);
      oB1 = __builtin_amdgcn_mfma_f32_32x32x16_bf16(v1, fbv, oB1, 0, 0, 0);
      __builtin_amdgcn_s_setprio(0);
    }

    // ---- write next tile into the other buffer, then sync
    if (it < KC / 64 - 1) {
      *(uint32x4*)&Kl[cur ^ 1][sr][scs0] = kreg0;
      *(uint32x4*)&Kl[cur ^ 1][sr][scs1] = kreg1;
      *(uint32x4*)&Vl[cur ^ 1][sr][scs0] = vreg0;
      *(uint32x4*)&Vl[cur ^ 1][sr][scs1] = vreg1;
      __syncthreads();
    }
  }

  // ---- epilogue: store UNNORMALIZED O (f32) and l for both q-groups
  const int qrowA = qb * 256 + wave * 64 + lq;
  float* OpA = Opart + (((size_t)split * NH + h) * S_LEN + qrowA) * 64;
  float* OpB = OpA + (size_t)32 * 64;
#pragma unroll
  for (int tq = 0; tq < 4; ++tq) {
    f32x4 a, b, c, d;
#pragma unroll
    for (int cc = 0; cc < 4; ++cc) {
      a[cc] = oA0[tq * 4 + cc]; b[cc] = oA1[tq * 4 + cc];
      c[cc] = oB0[tq * 4 + cc]; d[cc] = oB1[tq * 4 + cc];
    }
    *(f32x4*)(OpA + tq * 8 + hi * 4) = a;
    *(f32x4*)(OpA + 32 + tq * 8 + hi * 4) = b;
    *(f32x4*)(OpB + tq * 8 + hi * 4) = c;
    *(f32x4*)(OpB + 32 + tq * 8 + hi * 4) = d;
  }
  if (hi == 0) {
    Lpart[((size_t)split * NH + h) * S_LEN + qrowA] = lA;
    Lpart[((size_t)split * NH + h) * S_LEN + qrowA + 32] = lB;
  }
}

// ---------------- merge the KS partials -> AO (bf16) --------------------------
template <int KS>
__global__ __launch_bounds__(256) void attn_merge(const float* __restrict__ Opart,
                                                  const float* __restrict__ Lpart,
                                                  __bf16* __restrict__ AO) {
  int idx = blockIdx.x * 256 + threadIdx.x;  // NH*S*16 threads
  int dd = (idx & 15) * 4;
  int hq = idx >> 4;                          // h*S + q
  int q = hq & (S_LEN - 1), h = hq >> 12;
  float l = 0.f;
  f32x4 acc = f32x4{0.f, 0.f, 0.f, 0.f};
#pragma unroll
  for (int s = 0; s < KS; ++s) {
    l += Lpart[(size_t)s * NH * S_LEN + hq];
    f32x4 a = *(const f32x4*)&Opart[((size_t)s * NH * S_LEN + hq) * 64 + dd];
#pragma unroll
    for (int c = 0; c < 4; ++c) acc[c] += a[c];
  }
  float inv = 1.0f / fmaxf(l, 1e-30f);
  bf16x4 o;
#pragma unroll
  for (int c = 0; c < 4; ++c) o[c] = (__bf16)(acc[c] * inv);
  *(bf16x4*)&AO[(size_t)q * DMODEL + h * HDIM + dd] = o;
}

// ------------------------------------------------------------------------------
extern "C" void kernel_launch(void* const* d_in, const int* in_sizes, int n_in,
                              void* d_out, int out_size, void* d_ws, size_t ws_size,
                              hipStream_t stream) {
  const float* X = (const float*)d_in[0];
  const float* freqs = (const float*)d_in[1];
  const float* mask = (const float*)d_in[2];
  const float* wq = (const float*)d_in[3];
  const float* wk = (const float*)d_in[4];
  const float* wv = (const float*)d_in[5];
  const float* wo = (const float*)d_in[6];
  float* out = (float*)d_out;

  __bf16* WTqkv = (__bf16*)d_ws;                       // 3072*1024  (WoT follows)
  __bf16* WoT = WTqkv + 3072 * 1024;                   // 1024*1024
  __bf16* Xb = WoT + 1024 * 1024;                      // 4096*1024
  __bf16* Qb = Xb + (size_t)S_LEN * DMODEL;
  __bf16* Kb = Qb + (size_t)NH * S_LEN * HDIM;
  __bf16* Vtb = Kb + (size_t)NH * S_LEN * HDIM;        // V^T written directly by GEMM
  __bf16* AO = Vtb + (size_t)NH * S_LEN * HDIM;

  float* Opart = (float*)(AO + (size_t)S_LEN * DMODEL);
  float* Lpart = Opart + (size_t)KSPLIT * NH * S_LEN * 64;
  float* maskadd = Lpart + (size_t)KSPLIT * NH * S_LEN;

  convert_f32_bf16<<<dim3(S_LEN * DMODEL / 1024), 256, 0, stream>>>(X, Xb, mask, maskadd);

  // all 4 weight transposes in one launch (dsts contiguous: WTqkv then WoT)
  transpose_w4<<<dim3(16, 16, 4), 256, 0, stream>>>(wq, wk, wv, wo, WTqkv);

  // QKV projection with FUSED RoPE (Q,K) + FUSED V-transpose
  gemm_bt<1><<<dim3(32, 24), 256, 0, stream>>>(Xb, WTqkv, Qb, Kb, Vtb, freqs, nullptr, 1024, 3072);

  attn_split<KSPLIT><<<dim3(16 * NH * KSPLIT), 256, 0, stream>>>(Qb, Kb, Vtb, maskadd, Opart, Lpart);
  attn_merge<KSPLIT><<<dim3(NH * S_LEN * 16 / 256), 256, 0, stream>>>(Opart, Lpart, AO);

  gemm_bt<0><<<dim3(32, 8), 256, 0, stream>>>(AO, WoT, nullptr, nullptr, nullptr, nullptr, out, 1024, 1024);
}